// Round 2
// baseline (54.056 us; speedup 1.0000x reference)
//
#include <hip/hip_runtime.h>

// WaveletMask: y = HaarInv( HaarFwd(x) .* weight-mosaic )
// x, weight: (1,1,128,128) fp32; y: (1,1,128,128) fp32.
//
// Per 2x2 block (i,j), i,j in [0,64):
//   a=x[2i,2j] b=x[2i,2j+1] c=x[2i+1,2j] d=x[2i+1,2j+1]
//   ll=(a+b+c+d)/2  lh=(a+b-c-d)/2  hl=(a-b+c-d)/2  hh=(a-b-c+d)/2
//   ll*=W[i,j]; lh*=W[i,j+64]; hl*=W[i+64,j]; hh*=W[i+64,j+64]
//   y[2i,2j]  =(ll+lh+hl+hh)/2   y[2i,2j+1]=(ll+lh-hl-hh)/2
//   y[2i+1,2j]=(ll-lh+hl-hh)/2   y[2i+1,2j+1]=(ll-lh-hl+hh)/2
//
// This version: one thread per PAIR of adjacent 2x2 blocks -> 2048 threads,
// float4 loads/stores on x/y rows, float2 loads on each weight quadrant.
// 32 blocks x 64 threads = one wave per CU on 32 CUs (latency-min config).

#define H 128
#define HB 64

__device__ __forceinline__ void haar_block(float a, float b, float c, float d,
                                           float wll, float wlh, float whl, float whh,
                                           float& oa, float& ob, float& oc, float& od) {
    float ll = (a + b + c + d) * 0.5f * wll;
    float lh = (a + b - c - d) * 0.5f * wlh;
    float hl = (a - b + c - d) * 0.5f * whl;
    float hh = (a - b - c + d) * 0.5f * whh;
    oa = (ll + lh + hl + hh) * 0.5f;
    ob = (ll + lh - hl - hh) * 0.5f;
    oc = (ll - lh + hl - hh) * 0.5f;
    od = (ll - lh - hl + hh) * 0.5f;
}

__global__ __launch_bounds__(64) void wavelet_mask_kernel(
    const float* __restrict__ x, const float* __restrict__ w,
    float* __restrict__ y) {
    int t = blockIdx.x * blockDim.x + threadIdx.x;  // 0..2047
    int i  = t >> 5;       // haar block row, 0..63
    int jq = t & 31;       // pair-of-blocks col, 0..31 (covers cols 4jq..4jq+3)

    // x rows 2i, 2i+1: one float4 each (two adjacent 2x2 blocks)
    const float4 top = *reinterpret_cast<const float4*>(x + (2 * i) * H + 4 * jq);
    const float4 bot = *reinterpret_cast<const float4*>(x + (2 * i + 1) * H + 4 * jq);

    // weight quadrants, two adjacent cols each
    const float2 wll = *reinterpret_cast<const float2*>(w + i * H + 2 * jq);
    const float2 wlh = *reinterpret_cast<const float2*>(w + i * H + HB + 2 * jq);
    const float2 whl = *reinterpret_cast<const float2*>(w + (i + HB) * H + 2 * jq);
    const float2 whh = *reinterpret_cast<const float2*>(w + (i + HB) * H + HB + 2 * jq);

    float4 out0, out1;
    haar_block(top.x, top.y, bot.x, bot.y, wll.x, wlh.x, whl.x, whh.x,
               out0.x, out0.y, out1.x, out1.y);
    haar_block(top.z, top.w, bot.z, bot.w, wll.y, wlh.y, whl.y, whh.y,
               out0.z, out0.w, out1.z, out1.w);

    *reinterpret_cast<float4*>(y + (2 * i) * H + 4 * jq) = out0;
    *reinterpret_cast<float4*>(y + (2 * i + 1) * H + 4 * jq) = out1;
}

extern "C" void kernel_launch(void* const* d_in, const int* in_sizes, int n_in,
                              void* d_out, int out_size, void* d_ws, size_t ws_size,
                              hipStream_t stream) {
    const float* x = (const float*)d_in[0];
    const float* w = (const float*)d_in[1];
    float* y = (float*)d_out;
    // 2048 threads: 32 blocks x 64 (1 wave per CU across 32 CUs)
    wavelet_mask_kernel<<<32, 64, 0, stream>>>(x, w, y);
}